// Round 14
// baseline (8569.553 us; speedup 1.0000x reference)
//
#include <hip/hip_runtime.h>

// ============================================================================
// 2-layer LSTM, persistent kernel, MI355X — round 14 (u32 tiles, 1 WG/CU).
// R13 null (BARL ~= R7) falsified the barrier-drain theory. Consistent story:
// LLC CONTENTION — h reads are nt (never L2-cached), each h slice re-read by
// 64 u-tile WGs -> 96 MB/phase of LLC reads in phase-locked bursts -> queueing
// inflates latency ~3x (bottom-up model says 6-7us/phase; observed 16.6).
// R14: u32 per WG -> 256 WGs (128 L0 + 128 L1), h re-read 32x -> 48 MB/phase.
// Register cost (acc 128 + W dbuf 128 + v 32 ~ 320) fits because LDS ~106KB
// -> 1 WG/CU -> 1 wave/SIMD -> 512-reg budget (launch_bounds(256,1)).
// Everything else from R13: BARL windows (loads in flight across barriers),
// packed weights (wconv UNCHANGED; key = uidx*4+s), kway k-split + reduce2,
// nt h loads + sc01 h stores, leader-tree gridbar (targets 32/group).
// ============================================================================

typedef unsigned int u32;
typedef unsigned short u16;
typedef __attribute__((ext_vector_type(8))) short bf16x8;
typedef __attribute__((ext_vector_type(4))) float f32x4;

#define MFMA __builtin_amdgcn_mfma_f32_16x16x32_bf16
#define HB (256 * 1024)   // h buffer elems per parity

// LDS-publish barrier: ds ops complete, global loads STAY IN FLIGHT.
#define BARL() do {                                                            \
  asm volatile("s_waitcnt lgkmcnt(0)" ::: "memory");                           \
  __builtin_amdgcn_s_barrier();                                                \
  asm volatile("" ::: "memory");                                               \
} while (0)

__device__ __forceinline__ u16 f2bf(float f) {
  u32 u = __float_as_uint(f);
  u += 0x7fffu + ((u >> 16) & 1u);   // RNE (inputs finite)
  return (u16)(u >> 16);
}
__device__ __forceinline__ float sigm(float v) { return 1.f / (1.f + __expf(-v)); }
__device__ __forceinline__ float tanh_(float v) { return 1.f - 2.f / (__expf(2.f * v) + 1.f); }

__device__ __forceinline__ u32 ld_u32_sc01(const u32* p) {
  u32 v;
  asm volatile("global_load_dword %0, %1, off sc0 sc1\n\ts_waitcnt vmcnt(0)"
               : "=v"(v) : "v"(p) : "memory");
  return v;
}
__device__ __forceinline__ void st_u32_sc01(u32* p, u32 v) {
  asm volatile("global_store_dword %0, %1, off sc0 sc1" :: "v"(p), "v"(v) : "memory");
}
__device__ __forceinline__ void st_f32_sc01(float* p, float v) {
  asm volatile("global_store_dword %0, %1, off sc0 sc1" :: "v"(p), "v"(v) : "memory");
}

// ---------------- prologue: f32 -> bf16 packed-fragment weights ----------------
// (verbatim from R7)
__global__ void __launch_bounds__(256) wconv(
    const float* __restrict__ Wx0, const float* __restrict__ Wh0,
    const float* __restrict__ Wx1, const float* __restrict__ Wh1,
    u16* __restrict__ W1p, u16* __restrict__ W0p, u16* __restrict__ X0p) {
  const u32 NG1 = 1048576u, NG0 = 524288u, NGX = 32768u;
  u32 g = blockIdx.x * 256u + threadIdx.x;
  const float* src; u16* dst;
  if (g < NG1) {
    u32 lane = g & 63u, f = (g >> 6) & 1u, jj = (g >> 7) & 1u, c = (g >> 8) & 7u;
    u32 kway = (g >> 11) & 3u, s = (g >> 13) & 1u, u0idx = g >> 14;
    u32 i15 = lane & 15u, kq = lane >> 4;
    u32 row = (2u * f + (i15 >> 3)) * 1024u + u0idx * 16u + s * 8u + (i15 & 7u);
    u32 k = (kway + 4u * (2u * c + jj)) * 32u + kq * 8u;
    src = (k < 1024u) ? Wx1 + (size_t)row * 1024 + k
                      : Wh1 + (size_t)row * 1024 + (k - 1024u);
    dst = W1p + (size_t)g * 8;
  } else if (g < NG1 + NG0) {
    u32 h = g - NG1;
    u32 lane = h & 63u, f = (h >> 6) & 1u, jj = (h >> 7) & 1u, c = (h >> 8) & 3u;
    u32 kway = (h >> 10) & 3u, s = (h >> 12) & 1u, u0idx = h >> 13;
    u32 i15 = lane & 15u, kq = lane >> 4;
    u32 row = (2u * f + (i15 >> 3)) * 1024u + u0idx * 16u + s * 8u + (i15 & 7u);
    u32 k = (kway + 4u * (2u * c + jj)) * 32u + kq * 8u;
    src = Wh0 + (size_t)row * 1024 + k;
    dst = W0p + (size_t)h * 8;
  } else if (g < NG1 + NG0 + NGX) {
    u32 h = g - NG1 - NG0;
    u32 lane = h & 63u, f = (h >> 6) & 1u, kway = (h >> 7) & 1u;
    u32 s = (h >> 8) & 1u, u0idx = h >> 9;
    u32 i15 = lane & 15u, kq = lane >> 4;
    u32 row = (2u * f + (i15 >> 3)) * 1024u + u0idx * 16u + s * 8u + (i15 & 7u);
    u32 k = kway * 32u + kq * 8u;
    src = Wx0 + (size_t)row * 64 + k;
    dst = X0p + (size_t)h * 8;
  } else return;
  float4 v0 = *(const float4*)src, v1 = *(const float4*)(src + 4);
  bf16x8 r;
  r[0] = (short)f2bf(v0.x); r[1] = (short)f2bf(v0.y);
  r[2] = (short)f2bf(v0.z); r[3] = (short)f2bf(v0.w);
  r[4] = (short)f2bf(v1.x); r[5] = (short)f2bf(v1.y);
  r[6] = (short)f2bf(v1.z); r[7] = (short)f2bf(v1.w);
  *(bf16x8*)dst = r;
}

// ---- per-chunk weight load: 4 s-slices, dbuf bank, per-call opaque ----
#define LDW(bank, c) do {                                                      \
  u32 o0_ = bW[0] + (u32)((c) * 2048), o1_ = bW[1] + (u32)((c) * 2048);        \
  u32 o2_ = bW[2] + (u32)((c) * 2048), o3_ = bW[3] + (u32)((c) * 2048);        \
  asm volatile("" : "+v"(o0_), "+v"(o1_), "+v"(o2_), "+v"(o3_));               \
  _Pragma("unroll")                                                            \
  for (int jj_ = 0; jj_ < 2; ++jj_)                                            \
    _Pragma("unroll")                                                          \
    for (int f_ = 0; f_ < 2; ++f_) {                                           \
      W[bank][jj_][0][f_] = *(const bf16x8*)(WP + o0_ + (u32)(jj_*1024+f_*512));\
      W[bank][jj_][1][f_] = *(const bf16x8*)(WP + o1_ + (u32)(jj_*1024+f_*512));\
      W[bank][jj_][2][f_] = *(const bf16x8*)(WP + o2_ + (u32)(jj_*1024+f_*512));\
      W[bank][jj_][3][f_] = *(const bf16x8*)(WP + o3_ + (u32)(jj_*1024+f_*512));\
    }                                                                          \
} while (0)

// ---- per-chunk MFMA: 2 jj x 4 mf x 8 (s,f) = 64 MFMA ----
#define CHUNK(bank) do {                                                       \
  _Pragma("unroll")                                                            \
  for (int jj_ = 0; jj_ < 2; ++jj_) {                                          \
    const int kin_ = (kway + (jj_ << 2)) << 5;                                 \
    _Pragma("unroll")                                                          \
    for (int mf_ = 0; mf_ < 4; ++mf_) {                                        \
      bf16x8 a_ = readA(mf_, kin_);                                            \
      _Pragma("unroll")                                                        \
      for (int s_ = 0; s_ < 4; ++s_)                                           \
        _Pragma("unroll")                                                      \
        for (int f_ = 0; f_ < 2; ++f_)                                         \
          acc[mf_][s_][f_] = MFMA(a_, W[bank][jj_][s_][f_],                    \
                                  acc[mf_][s_][f_], 0, 0, 0);                  \
    }                                                                          \
  }                                                                            \
} while (0)

__global__ void __launch_bounds__(256, 1)
lstm_persist(const float* __restrict__ x,
             const float* __restrict__ b0, const float* __restrict__ b1,
             const float* __restrict__ fcW, const float* __restrict__ fcb,
             const u16* __restrict__ W1p, const u16* __restrict__ W0p,
             const u16* __restrict__ X0p,
             u16* __restrict__ h0b, u16* __restrict__ h1b,
             float* __restrict__ h1f, u32* __restrict__ bar,
             float* __restrict__ out)
{
  const int tid = threadIdx.x, blk = blockIdx.x;
  const int lane = tid & 63, w = tid >> 6;
  const int kway = w;                 // wave = k-split lane (0..3)
  const int L = blk >> 7;             // 0: layer0 WG (blk<128), 1: layer1
  const int sub = blk & 127;
  const int m0 = (sub >> 5) << 6;     // 4 m-tiles of 64 rows
  const int uidx = sub & 31;          // u-tile of 32 units
  const int u0 = uidx << 5;

  __shared__ short Abuf[64 * 256];    // 32KB staged A chunk
  __shared__ float gA[64][132];       // k-reduce region A (128 gate cols +pad)
  __shared__ float gB[64][132];       // k-reduce region B
  __shared__ float cbuf[64][32];      // persistent c state (own layer)

  for (int i = tid; i < 64 * 32; i += 256) ((float*)cbuf)[i] = 0.f;

  const int i15 = lane & 15, kq = lane >> 4;

  // packed-weight base offsets, 4 s-slices (key = uidx*4 + s; wconv unchanged)
  u32 bW[4], bX[4];
#pragma unroll
  for (int s_ = 0; s_ < 4; ++s_) {
    u32 key = (u32)((uidx << 2) + s_);
    bW[s_] = ((key << 2) | (u32)kway) * (L ? 16384u : 8192u) + (u32)lane * 8u;
    bX[s_] = ((key << 1) | (u32)kway) * 1024u + (u32)lane * 8u;  // kway<2 only
  }
  const u16* WP = L ? W1p : W0p;

  float bias[4][2];
#pragma unroll
  for (int s_ = 0; s_ < 4; ++s_)
#pragma unroll
    for (int f_ = 0; f_ < 2; ++f_) {
      int rowf = ((f_ << 1) + (i15 >> 3)) * 1024 + u0 + s_ * 8 + (i15 & 7);
      bias[s_][f_] = (kway == 0) ? (L ? b1[rowf] : b0[rowf]) : 0.f;
    }

  // staging maps: 2048 bf16x8 slots (64 rows x 32), 8 per thread (R13)
  int grow[8], ldsoff[8];
#pragma unroll
  for (int cc = 0; cc < 8; ++cc) {
    int slot = cc * 256 + tid;
    int row = slot >> 5, c = slot & 31;
    grow[cc]   = ((m0 + row) << 10) + (c << 3);
    ldsoff[cc] = (row << 8) + ((c ^ (row & 7)) << 3);
  }

  bf16x8 v[8];
  auto stage_ld = [&](const u16* src, int kbase) {   // nt: LLC-coherent reads
#pragma unroll
    for (int cc = 0; cc < 8; ++cc)
      v[cc] = __builtin_nontemporal_load((const bf16x8*)(src + grow[cc] + kbase));
  };
  auto stage_st = [&]() {
#pragma unroll
    for (int cc = 0; cc < 8; ++cc)
      *(bf16x8*)&Abuf[ldsoff[cc]] = v[cc];
  };

  auto stage_x = [&](int t) {   // x tile 64x64 f32 -> bf16 into Abuf
    int row = tid >> 2, c4 = tid & 3;
    const float* g = x + ((size_t)(m0 + row) * 512 + t) * 64 + (c4 << 4);
    float4 a0 = *(const float4*)g,       a1 = *(const float4*)(g + 4);
    float4 a2 = *(const float4*)(g + 8), a3 = *(const float4*)(g + 12);
    bf16x8 r0, r1;
    r0[0] = (short)f2bf(a0.x); r0[1] = (short)f2bf(a0.y);
    r0[2] = (short)f2bf(a0.z); r0[3] = (short)f2bf(a0.w);
    r0[4] = (short)f2bf(a1.x); r0[5] = (short)f2bf(a1.y);
    r0[6] = (short)f2bf(a1.z); r0[7] = (short)f2bf(a1.w);
    r1[0] = (short)f2bf(a2.x); r1[1] = (short)f2bf(a2.y);
    r1[2] = (short)f2bf(a2.z); r1[3] = (short)f2bf(a2.w);
    r1[4] = (short)f2bf(a3.x); r1[5] = (short)f2bf(a3.y);
    r1[6] = (short)f2bf(a3.z); r1[7] = (short)f2bf(a3.w);
    int c = c4 << 1;
    *(bf16x8*)&Abuf[(row << 8) + (((c    ) ^ (row & 7)) << 3)] = r0;
    *(bf16x8*)&Abuf[(row << 8) + (((c + 1) ^ (row & 7)) << 3)] = r1;
  };

  auto readA = [&](int mf, int kin) -> bf16x8 {
    int row = (mf << 4) | i15;
    int c = ((kin >> 3) + kq) ^ (row & 7);
    return *(const bf16x8*)&Abuf[(row << 8) + (c << 3)];
  };

  bf16x8 W[2][2][4][2];   // [bank][jj][s][f] dbuf weights (128 regs)
  f32x4 acc[4][4][2];     // [mf][s][f] (128 regs)

  auto acc_init = [&]() {
#pragma unroll
    for (int mf = 0; mf < 4; ++mf)
#pragma unroll
      for (int s_ = 0; s_ < 4; ++s_)
#pragma unroll
        for (int f_ = 0; f_ < 2; ++f_) {
          float bv = bias[s_][f_];
          acc[mf][s_][f_][0] = bv; acc[mf][s_][f_][1] = bv;
          acc[mf][s_][f_][2] = bv; acc[mf][s_][f_][3] = bv;
        }
  };

  auto reduce2 = [&]() {   // 4 kway partials -> gA + gB
    if (kway < 2) {
      float (*g)[132] = kway ? gB : gA;
#pragma unroll
      for (int mf = 0; mf < 4; ++mf)
#pragma unroll
        for (int s_ = 0; s_ < 4; ++s_)
#pragma unroll
          for (int f_ = 0; f_ < 2; ++f_)
#pragma unroll
            for (int r = 0; r < 4; ++r)
              g[(mf << 4) + (kq << 2) + r][(s_ << 5) + (f_ << 4) + i15] = acc[mf][s_][f_][r];
    }
    __syncthreads();
    if (kway >= 2) {
      float (*g)[132] = (kway == 3) ? gB : gA;
#pragma unroll
      for (int mf = 0; mf < 4; ++mf)
#pragma unroll
        for (int s_ = 0; s_ < 4; ++s_)
#pragma unroll
          for (int f_ = 0; f_ < 2; ++f_)
#pragma unroll
            for (int r = 0; r < 4; ++r)
              g[(mf << 4) + (kq << 2) + r][(s_ << 5) + (f_ << 4) + i15] += acc[mf][s_][f_][r];
    }
    __syncthreads();
  };

  auto ew = [&](u16* hdst, bool wf32) {
    int row = tid >> 2, un = (tid & 3) << 3;   // 8 units per thread
    float hq[8];
#pragma unroll
    for (int q = 0; q < 8; ++q) {
      int u = un + q;
      int cb = ((u >> 3) << 5) | (u & 7);
      float gi = gA[row][cb]      + gB[row][cb];
      float gf = gA[row][cb + 8]  + gB[row][cb + 8];
      float gg = gA[row][cb + 16] + gB[row][cb + 16];
      float go = gA[row][cb + 24] + gB[row][cb + 24];
      float ii = sigm(gi), ff = sigm(gf), g2 = tanh_(gg), oo = sigm(go);
      float c = ff * cbuf[row][u] + ii * g2;
      cbuf[row][u] = c;
      hq[q] = oo * tanh_(c);
    }
    size_t idx = ((size_t)(m0 + row) << 10) + u0 + un;
#pragma unroll
    for (int q = 0; q < 4; ++q)
      st_u32_sc01((u32*)(hdst + idx + 2 * q),
                  (u32)f2bf(hq[2 * q]) | ((u32)f2bf(hq[2 * q + 1]) << 16));
    if (wf32) {
#pragma unroll
      for (int q = 0; q < 8; ++q) st_f32_sc01(h1f + idx + q, hq[q]);
    }
  };

  auto gridbar = [&](int t) {       // leader-tree barrier (targets: 32/group)
    __syncthreads();                // FULL drain: sc01 h stores reach LLC
    if (tid == 0) {
      const int g = blk & 7;
      u32* gc   = bar + g * 32;
      u32* root = bar + 256;
      u32* gen  = bar + 288 + g * 32;
      const u32 p1 = (u32)(t + 1);
      __hip_atomic_fetch_add(gc, 1u, __ATOMIC_RELAXED, __HIP_MEMORY_SCOPE_AGENT);
      if (blk < 8) {
        while (ld_u32_sc01(gc) < 32u * p1) __builtin_amdgcn_s_sleep(4);
        __hip_atomic_fetch_add(root, 1u, __ATOMIC_RELAXED, __HIP_MEMORY_SCOPE_AGENT);
        while (ld_u32_sc01(root) < 8u * p1) __builtin_amdgcn_s_sleep(2);
        st_u32_sc01(gen, p1);
      } else {
        while (ld_u32_sc01(gen) < p1) __builtin_amdgcn_s_sleep(4);
      }
    }
    __syncthreads();
  };

  if (L == 0) {
    // ---------------- layer-0 WGs: compute h0(t) each phase ----------------
#pragma unroll 1
    for (int t = 0; t <= 512; ++t) {
      if (t < 512) {
        const u16* h0rd = h0b + ((t + 1) & 1) * HB;
        u16* h0wr = h0b + (t & 1) * HB;
        acc_init();
        stage_x(t);                        // Abuf <- x tile (ds writes)
        stage_ld(h0rd, 0);                 // prefetch h0 chunk0 (in flight)
        bf16x8 X[4][2];
        if (kway < 2) {
          u32 ox0 = bX[0], ox1 = bX[1], ox2 = bX[2], ox3 = bX[3];
          asm volatile("" : "+v"(ox0), "+v"(ox1), "+v"(ox2), "+v"(ox3));
          X[0][0] = *(const bf16x8*)(X0p + ox0);
          X[0][1] = *(const bf16x8*)(X0p + ox0 + 512u);
          X[1][0] = *(const bf16x8*)(X0p + ox1);
          X[1][1] = *(const bf16x8*)(X0p + ox1 + 512u);
          X[2][0] = *(const bf16x8*)(X0p + ox2);
          X[2][1] = *(const bf16x8*)(X0p + ox2 + 512u);
          X[3][0] = *(const bf16x8*)(X0p + ox3);
          X[3][1] = *(const bf16x8*)(X0p + ox3 + 512u);
        }
        LDW(0, 0);                         // W chunk0 -> bank0
        BARL();                            // x tile published (vm in flight)
        if (kway < 2) {                    // x-tick (ksteps 0,1 of K=64)
          const int kin = kway << 5;
#pragma unroll
          for (int mf = 0; mf < 4; ++mf) {
            bf16x8 a = readA(mf, kin);
#pragma unroll
            for (int s_ = 0; s_ < 4; ++s_)
#pragma unroll
              for (int f_ = 0; f_ < 2; ++f_)
                acc[mf][s_][f_] = MFMA(a, X[s_][f_], acc[mf][s_][f_], 0, 0, 0);
          }
        }
        BARL();                            // x consumed
        stage_st(); BARL();                // Abuf <- h0 chunk0
        stage_ld(h0rd, 256); LDW(1, 1); CHUNK(0); BARL();
        stage_st(); BARL();
        stage_ld(h0rd, 512); LDW(0, 2); CHUNK(1); BARL();
        stage_st(); BARL();
        stage_ld(h0rd, 768); LDW(1, 3); CHUNK(0); BARL();
        stage_st(); BARL();
        CHUNK(1);
        reduce2();
        ew(h0wr, false);
      }
      gridbar(t);
    }
  } else {
    // -------------- layer-1 WGs: compute h1(t-1) each phase --------------
#pragma unroll 1
    for (int t = 0; t <= 512; ++t) {
      if (t >= 1) {
        const u16* h0rd = h0b + ((t + 1) & 1) * HB;   // h0(t-1)
        const u16* h1rd = h1b + (t & 1) * HB;         // h1(t-2)
        u16* h1wr = h1b + ((t + 1) & 1) * HB;         // h1(t-1)
        acc_init();
        stage_ld(h0rd, 0); LDW(0, 0);
        stage_st(); BARL();
        stage_ld(h0rd, 256); LDW(1, 1); CHUNK(0); BARL();
        stage_st(); BARL();
        stage_ld(h0rd, 512); LDW(0, 2); CHUNK(1); BARL();
        stage_st(); BARL();
        stage_ld(h0rd, 768); LDW(1, 3); CHUNK(0); BARL();
        stage_st(); BARL();
        stage_ld(h1rd, 0);   LDW(0, 4); CHUNK(1); BARL();
        stage_st(); BARL();
        stage_ld(h1rd, 256); LDW(1, 5); CHUNK(0); BARL();
        stage_st(); BARL();
        stage_ld(h1rd, 512); LDW(0, 6); CHUNK(1); BARL();
        stage_st(); BARL();
        stage_ld(h1rd, 768); LDW(1, 7); CHUNK(0); BARL();
        stage_st(); BARL();
        CHUNK(1);
        reduce2();
        ew(h1wr, t == 512);
      }
      gridbar(t);
    }
  }

  // ---------------- fc epilogue: out = h1(511) @ fcW.T + fcb ----------------
  if (blk < 64) {
    const int row = (blk << 2) | w;
    const float* hrow = h1f + ((size_t)row << 10);
#pragma unroll 1
    for (int o = 0; o < 12; ++o) {
      const float* wrow = fcW + o * 1024;
      float p = 0.f;
#pragma unroll
      for (int j = 0; j < 16; ++j) {
        int k = (j << 6) | lane;
        p += __builtin_nontemporal_load(hrow + k) * wrow[k];
      }
#pragma unroll
      for (int off = 32; off > 0; off >>= 1) p += __shfl_down(p, off, 64);
      if (lane == 0) out[row * 12 + o] = p + fcb[o];
    }
  }
}

extern "C" void kernel_launch(void* const* d_in, const int* in_sizes, int n_in,
                              void* d_out, int out_size, void* d_ws, size_t ws_size,
                              hipStream_t stream) {
  (void)in_sizes; (void)n_in; (void)out_size; (void)ws_size;
  const float* x   = (const float*)d_in[0];
  const float* Wx0 = (const float*)d_in[1];
  const float* Wh0 = (const float*)d_in[2];
  const float* b0  = (const float*)d_in[3];
  const float* Wx1 = (const float*)d_in[4];
  const float* Wh1 = (const float*)d_in[5];
  const float* b1  = (const float*)d_in[6];
  const float* fcW = (const float*)d_in[7];
  const float* fcb = (const float*)d_in[8];

  char* ws = (char*)d_ws;
  u16* W1p   = (u16*)ws;                          // 16 MiB packed Wx1|Wh1
  u16* W0p   = (u16*)(ws + (16u << 20));          //  8 MiB packed Wh0
  u16* X0p   = (u16*)(ws + (24u << 20));          // 512 KiB packed Wx0
  u16* h0b   = (u16*)(ws + (25u << 20));          // 2 x 512 KiB
  u16* h1b   = (u16*)(ws + (26u << 20));          // 2 x 512 KiB
  float* h1f = (float*)(ws + (27u << 20));        // 1 MiB
  u32* bar   = (u32*)(ws + (28u << 20));          // counters

  hipMemsetAsync(ws + (25u << 20) + (1 << 19), 0, 1 << 19, stream);  // h0b[1]
  hipMemsetAsync(ws + (26u << 20) + (1 << 19), 0, 1 << 19, stream);  // h1b[1]
  hipMemsetAsync(bar, 0, 4096, stream);

  wconv<<<6272, 256, 0, stream>>>(Wx0, Wh0, Wx1, Wh1, W1p, W0p, X0p);
  lstm_persist<<<256, 256, 0, stream>>>(x, b0, b1, fcW, fcb,
                                        W1p, W0p, X0p,
                                        h0b, h1b, h1f, bar, (float*)d_out);
}